// Round 1
// baseline (2110.700 us; speedup 1.0000x reference)
//
#include <hip/hip_runtime.h>
#include <hip/hip_bf16.h>

#define Bv 8
#define Tv 64
#define Nv 128
#define P2v 256
#define KSv 64

// ---------------------------------------------------------------------------
// Kernel A: per (b,t): Q = X@W_Q (128x64), K = X@W_K (128x64) in LDS,
//           S = Q K^T / 8  -> ws   (S layout: [B,T,N,N])
// ---------------------------------------------------------------------------
__global__ __launch_bounds__(256) void qk_scores_kernel(
    const float* __restrict__ x, const float* __restrict__ Wq,
    const float* __restrict__ Wk, float* __restrict__ S) {
  const int bt = blockIdx.x;  // 0..511
  const float* __restrict__ X = x + (size_t)bt * Nv * P2v;  // 128x256
  __shared__ float Qs[Nv][KSv];  // 32 KB
  __shared__ float Ks[Nv][KSv];  // 32 KB
  const int tid = threadIdx.x;
  const int lane = tid & 63;

  // Phase 1: Q,K GEMMs. o -> (i = o>>6, k = o&63). Within a wave: same i
  // (X row broadcast), consecutive k (W reads coalesced 256B).
  for (int o = tid; o < Nv * KSv; o += 256) {
    const int i = o >> 6;
    const int k = o & 63;
    const float* __restrict__ xr = X + i * P2v;
    float aq = 0.f, ak = 0.f;
#pragma unroll 8
    for (int p = 0; p < P2v; ++p) {
      const float xv = xr[p];
      aq += xv * Wq[p * KSv + k];
      ak += xv * Wk[p * KSv + k];
    }
    Qs[i][k] = aq;
    Ks[i][k] = ak;
  }
  __syncthreads();

  // Phase 2: S[i][j] = dot(Qs[i,:], Ks[j,:]) * 0.125
  // Lane-rotated k index -> both LDS reads spread 2 lanes/bank (free).
  float* __restrict__ Sb = S + (size_t)bt * Nv * Nv;
  for (int o = tid; o < Nv * Nv; o += 256) {
    const int i = o >> 7;
    const int j = o & 127;
    float acc = 0.f;
#pragma unroll
    for (int kk = 0; kk < KSv; ++kk) {
      const int k = (kk + lane) & 63;
      acc += Qs[i][k] * Ks[j][k];
    }
    Sb[o] = acc * 0.125f;
  }
}

// ---------------------------------------------------------------------------
// Kernel B: softmax over the T axis, in place on S.
// One thread per (b,i,j) line: 64 strided reads (coalesced across j within a
// wave), max/exp/sum in registers, one write pass.
// ---------------------------------------------------------------------------
__global__ __launch_bounds__(256) void softmax_t_kernel(float* __restrict__ S) {
  const int idx = blockIdx.x * 256 + threadIdx.x;  // 0 .. B*N*N-1
  const int j = idx & (Nv - 1);
  const int i = (idx >> 7) & (Nv - 1);
  const int b = idx >> 14;
  const size_t base = ((size_t)b * Tv * Nv * Nv) + (size_t)i * Nv + j;

  float vals[Tv];
  float m = -1e30f;
#pragma unroll
  for (int t = 0; t < Tv; ++t) {
    const float v = S[base + (size_t)t * Nv * Nv];
    vals[t] = v;
    m = fmaxf(m, v);
  }
  float s = 0.f;
#pragma unroll
  for (int t = 0; t < Tv; ++t) {
    const float e = __expf(vals[t] - m);
    vals[t] = e;
    s += e;
  }
  const float inv = 1.f / s;
#pragma unroll
  for (int t = 0; t < Tv; ++t) {
    S[base + (size_t)t * Nv * Nv] = vals[t] * inv;
  }
}

// ---------------------------------------------------------------------------
// Kernel C: per (b,t): V chunk (128 x 64 cols of P2) = X@W_V into LDS,
//           out[:, chunk] = A_t (from ws) @ Vchunk.  4 chunks.
// ---------------------------------------------------------------------------
__global__ __launch_bounds__(256) void av_out_kernel(
    const float* __restrict__ x, const float* __restrict__ Wv,
    const float* __restrict__ A, float* __restrict__ out) {
  const int bt = blockIdx.x;
  const float* __restrict__ X = x + (size_t)bt * Nv * P2v;
  const float* __restrict__ Ab = A + (size_t)bt * Nv * Nv;
  float* __restrict__ ob = out + (size_t)bt * Nv * P2v;
  __shared__ float Vs[Nv][64];  // 32 KB (one 64-column chunk of V)
  const int tid = threadIdx.x;

  for (int c = 0; c < 4; ++c) {
    __syncthreads();  // protect Vs from previous chunk's readers
    // Vs[j][k] = dot(X[j,:], Wv[:, c*64+k])
    for (int o = tid; o < Nv * 64; o += 256) {
      const int j = o >> 6;
      const int k = o & 63;
      const float* __restrict__ xr = X + j * P2v;
      const float* __restrict__ wc = Wv + (c * 64 + k);
      float acc = 0.f;
#pragma unroll 8
      for (int p = 0; p < P2v; ++p) {
        acc += xr[p] * wc[p * P2v];
      }
      Vs[j][k] = acc;
    }
    __syncthreads();
    // out[i][c*64+k] = sum_j A[i][j] * Vs[j][k]
    // Wave lanes: same i (A broadcast), consecutive k (Vs conflict-free).
    for (int o = tid; o < Nv * 64; o += 256) {
      const int i = o >> 6;
      const int k = o & 63;
      float acc = 0.f;
#pragma unroll 8
      for (int j = 0; j < Nv; ++j) {
        acc += Ab[i * Nv + j] * Vs[j][k];
      }
      ob[i * P2v + c * 64 + k] = acc;
    }
  }
}

extern "C" void kernel_launch(void* const* d_in, const int* in_sizes, int n_in,
                              void* d_out, int out_size, void* d_ws,
                              size_t ws_size, hipStream_t stream) {
  const float* x = (const float*)d_in[0];
  const float* Wq = (const float*)d_in[1];
  const float* Wk = (const float*)d_in[2];
  const float* Wv = (const float*)d_in[3];
  float* out = (float*)d_out;
  float* S = (float*)d_ws;  // B*T*N*N fp32 = 33.55 MB scratch

  const int BT = Bv * Tv;  // 512
  hipLaunchKernelGGL(qk_scores_kernel, dim3(BT), dim3(256), 0, stream, x, Wq,
                     Wk, S);
  const int lines = Bv * Nv * Nv;  // 131072
  hipLaunchKernelGGL(softmax_t_kernel, dim3(lines / 256), dim3(256), 0, stream,
                     S);
  hipLaunchKernelGGL(av_out_kernel, dim3(BT), dim3(256), 0, stream, x, Wv, S,
                     out);
}

// Round 2
// 89.211 us; speedup vs baseline: 23.6598x; 23.6598x over previous
//
#include <hip/hip_runtime.h>
#include <hip/hip_bf16.h>

#define Bv 8
#define Tv 64
#define Nv 128
#define P2v 256
#define KSv 64

typedef __attribute__((ext_vector_type(8))) short bf8;   // 8 bf16 in 4 VGPRs
typedef __attribute__((ext_vector_type(4))) float f4;    // MFMA C/D frag

#define MFMA16(a, b, c) __builtin_amdgcn_mfma_f32_16x16x32_bf16((a), (b), (c), 0, 0, 0)

union B8U {
  bf8 v;
  short s[8];
};

__device__ __forceinline__ unsigned short f2bf(float f) {
  unsigned u = __float_as_uint(f);
  return (unsigned short)((u + 0x7fffu + ((u >> 16) & 1u)) >> 16);
}
__device__ __forceinline__ float bf2f(unsigned short h) {
  return __uint_as_float(((unsigned)h) << 16);
}

// LDS [128][64] bf16, XOR-swizzled 16B granules: elem offset
__device__ __forceinline__ int qswz(int i, int ks) {
  int gin = ks >> 3;
  return i * 64 + ((gin ^ (i & 7)) << 3) + (ks & 7);
}
// LDS [256][128] bf16 (V^T), XOR-swizzled
__device__ __forceinline__ int vswz(int q, int j) {
  int gin = j >> 3;
  return q * 128 + ((gin ^ (q & 7)) << 3) + (j & 7);
}

// ---------------------------------------------------------------------------
// Prep: W_Q, W_K -> split hi/lo bf16 fragment-linear; W_V -> bf16 frag-linear.
// Fragment order: [p_tile][n_tile][lane][jj] with p = pt*32 + 8*(lane>>4)+jj,
// n = nt*16 + (lane&15). Kernel loads are then lane-consecutive 16B.
// ---------------------------------------------------------------------------
__global__ __launch_bounds__(256) void prep_w_kernel(
    const float* __restrict__ Wq, const float* __restrict__ Wk,
    const float* __restrict__ Wv, unsigned short* __restrict__ wqh,
    unsigned short* __restrict__ wql, unsigned short* __restrict__ wkh,
    unsigned short* __restrict__ wkl, unsigned short* __restrict__ wvf) {
  const int e = blockIdx.x * 256 + threadIdx.x;  // 0..98303
  if (e < 32768) {
    const float* W = (e < 16384) ? Wq : Wk;
    unsigned short* oh = (e < 16384) ? wqh : wkh;
    unsigned short* ol = (e < 16384) ? wql : wkl;
    const int t = e & 16383;
    const int jj = t & 7, lane = (t >> 3) & 63, nt = (t >> 9) & 3, pt = t >> 11;
    const int p = pt * 32 + 8 * (lane >> 4) + jj;
    const int n = nt * 16 + (lane & 15);
    const float v = W[p * KSv + n];
    const unsigned short h = f2bf(v);
    oh[t] = h;
    ol[t] = f2bf(v - bf2f(h));
  } else {
    const int t = e - 32768;  // 0..65535
    const int jj = t & 7, lane = (t >> 3) & 63, nt = (t >> 9) & 15, pt = t >> 13;
    const int p = pt * 32 + 8 * (lane >> 4) + jj;
    const int q = nt * 16 + (lane & 15);
    wvf[t] = f2bf(Wv[p * P2v + q]);
  }
}

// ---------------------------------------------------------------------------
// Kernel A: per (b,t): Q,K via bf16x3 MFMA (fp32-accurate), split to LDS,
// S = Q K^T / 8 via bf16x3 MFMA -> ws.  8 waves, 16 rows each.
// ---------------------------------------------------------------------------
__global__ __launch_bounds__(512) void qk_kernel(
    const float* __restrict__ x, const unsigned short* __restrict__ wqh,
    const unsigned short* __restrict__ wql,
    const unsigned short* __restrict__ wkh,
    const unsigned short* __restrict__ wkl, float* __restrict__ S) {
  __shared__ alignas(16) unsigned short qh_l[Nv * KSv];
  __shared__ alignas(16) unsigned short ql_l[Nv * KSv];
  __shared__ alignas(16) unsigned short kh_l[Nv * KSv];
  __shared__ alignas(16) unsigned short kl_l[Nv * KSv];
  const int bt = blockIdx.x;
  const float* __restrict__ X = x + (size_t)bt * (Nv * P2v);
  const int tid = threadIdx.x, lane = tid & 63, wid = tid >> 6;
  const int lg = lane >> 4, lr = lane & 15;
  const int r0 = wid * 16;

  const f4 zero = {0.f, 0.f, 0.f, 0.f};
  f4 aQ[4], aK[4];
#pragma unroll
  for (int n = 0; n < 4; ++n) {
    aQ[n] = zero;
    aK[n] = zero;
  }

  // Phase 1: Q = X@Wq, K = X@Wk (bf16x3)
  for (int kt = 0; kt < 8; ++kt) {
    const float* xr = X + (r0 + lr) * P2v + kt * 32 + lg * 8;
    const float4 x0 = *(const float4*)(xr);
    const float4 x1 = *(const float4*)(xr + 4);
    const float xs[8] = {x0.x, x0.y, x0.z, x0.w, x1.x, x1.y, x1.z, x1.w};
    B8U xh, xl;
#pragma unroll
    for (int j = 0; j < 8; ++j) {
      const unsigned short h = f2bf(xs[j]);
      xh.s[j] = (short)h;
      xl.s[j] = (short)f2bf(xs[j] - bf2f(h));
    }
#pragma unroll
    for (int n = 0; n < 4; ++n) {
      const int o = ((kt * 4 + n) * 64 + lane) * 8;
      const bf8 fqh = *(const bf8*)(wqh + o);
      const bf8 fql = *(const bf8*)(wql + o);
      const bf8 fkh = *(const bf8*)(wkh + o);
      const bf8 fkl = *(const bf8*)(wkl + o);
      aQ[n] = MFMA16(xh.v, fqh, aQ[n]);
      aQ[n] = MFMA16(xh.v, fql, aQ[n]);
      aQ[n] = MFMA16(xl.v, fqh, aQ[n]);
      aK[n] = MFMA16(xh.v, fkh, aK[n]);
      aK[n] = MFMA16(xh.v, fkl, aK[n]);
      aK[n] = MFMA16(xl.v, fkh, aK[n]);
    }
  }

  // Split Q,K to hi/lo bf16 in LDS (C-layout: row=4*lg+r, col=lr)
#pragma unroll
  for (int n = 0; n < 4; ++n) {
#pragma unroll
    for (int r = 0; r < 4; ++r) {
      const int i = r0 + 4 * lg + r;
      const int ks = n * 16 + lr;
      const int off = qswz(i, ks);
      const float qv = aQ[n][r], kv = aK[n][r];
      const unsigned short qh = f2bf(qv), kh = f2bf(kv);
      qh_l[off] = qh;
      ql_l[off] = f2bf(qv - bf2f(qh));
      kh_l[off] = kh;
      kl_l[off] = f2bf(kv - bf2f(kh));
    }
  }
  __syncthreads();

  // Phase 2: S = Q K^T / 8 (bf16x3)
  f4 aS[8];
#pragma unroll
  for (int n = 0; n < 8; ++n) aS[n] = zero;
#pragma unroll
  for (int kt = 0; kt < 2; ++kt) {
    const int qoff = qswz(r0 + lr, kt * 32 + lg * 8);
    const bf8 fqh = *(const bf8*)(qh_l + qoff);
    const bf8 fql = *(const bf8*)(ql_l + qoff);
#pragma unroll
    for (int n = 0; n < 8; ++n) {
      const int koff = qswz(n * 16 + lr, kt * 32 + lg * 8);
      const bf8 fkh = *(const bf8*)(kh_l + koff);
      const bf8 fkl = *(const bf8*)(kl_l + koff);
      aS[n] = MFMA16(fqh, fkh, aS[n]);
      aS[n] = MFMA16(fqh, fkl, aS[n]);
      aS[n] = MFMA16(fql, fkh, aS[n]);
    }
  }
  float* __restrict__ Sb = S + (size_t)bt * (Nv * Nv);
#pragma unroll
  for (int n = 0; n < 8; ++n) {
#pragma unroll
    for (int r = 0; r < 4; ++r) {
      Sb[(r0 + 4 * lg + r) * Nv + n * 16 + lr] = aS[n][r] * 0.125f;
    }
  }
}

// ---------------------------------------------------------------------------
// Kernel B: softmax over T axis, in place on S. (unchanged)
// ---------------------------------------------------------------------------
__global__ __launch_bounds__(256) void softmax_t_kernel(float* __restrict__ S) {
  const int idx = blockIdx.x * 256 + threadIdx.x;  // 0 .. B*N*N-1
  const int j = idx & (Nv - 1);
  const int i = (idx >> 7) & (Nv - 1);
  const int b = idx >> 14;
  const size_t base = ((size_t)b * Tv * Nv * Nv) + (size_t)i * Nv + j;

  float vals[Tv];
  float m = -1e30f;
#pragma unroll
  for (int t = 0; t < Tv; ++t) {
    const float v = S[base + (size_t)t * Nv * Nv];
    vals[t] = v;
    m = fmaxf(m, v);
  }
  float s = 0.f;
#pragma unroll
  for (int t = 0; t < Tv; ++t) {
    const float e = __expf(vals[t] - m);
    vals[t] = e;
    s += e;
  }
  const float inv = 1.f / s;
#pragma unroll
  for (int t = 0; t < Tv; ++t) {
    S[base + (size_t)t * Nv * Nv] = vals[t] * inv;
  }
}

// ---------------------------------------------------------------------------
// Kernel C: per (b,t): V = X@Wv (bf16 MFMA) -> V^T in LDS; out = A @ V.
// ---------------------------------------------------------------------------
__global__ __launch_bounds__(512) void av_kernel(
    const float* __restrict__ x, const unsigned short* __restrict__ wvf,
    const float* __restrict__ A, float* __restrict__ out) {
  __shared__ alignas(16) unsigned short vt[P2v * Nv];  // V^T [q][j], 64 KB
  const int bt = blockIdx.x;
  const float* __restrict__ X = x + (size_t)bt * (Nv * P2v);
  const float* __restrict__ Ab = A + (size_t)bt * (Nv * Nv);
  float* __restrict__ ob = out + (size_t)bt * (Nv * P2v);
  const int tid = threadIdx.x, lane = tid & 63, wid = tid >> 6;
  const int lg = lane >> 4, lr = lane & 15;
  const int r0 = wid * 16;

  const f4 zero = {0.f, 0.f, 0.f, 0.f};
  f4 aV[16];
#pragma unroll
  for (int n = 0; n < 16; ++n) aV[n] = zero;

  // V-projection (plain bf16: hi part only)
  for (int kt = 0; kt < 8; ++kt) {
    const float* xr = X + (r0 + lr) * P2v + kt * 32 + lg * 8;
    const float4 x0 = *(const float4*)(xr);
    const float4 x1 = *(const float4*)(xr + 4);
    const float xs[8] = {x0.x, x0.y, x0.z, x0.w, x1.x, x1.y, x1.z, x1.w};
    B8U xh;
#pragma unroll
    for (int j = 0; j < 8; ++j) xh.s[j] = (short)f2bf(xs[j]);
#pragma unroll
    for (int n = 0; n < 16; ++n) {
      const int o = ((kt * 16 + n) * 64 + lane) * 8;
      const bf8 wv = *(const bf8*)(wvf + o);
      aV[n] = MFMA16(xh.v, wv, aV[n]);
    }
  }
  // Write V^T to LDS
#pragma unroll
  for (int n = 0; n < 16; ++n) {
#pragma unroll
    for (int r = 0; r < 4; ++r) {
      const int q = n * 16 + lr;
      const int j = r0 + 4 * lg + r;
      vt[vswz(q, j)] = f2bf(aV[n][r]);
    }
  }
  __syncthreads();

  // out = A @ V
  f4 aO[16];
#pragma unroll
  for (int n = 0; n < 16; ++n) aO[n] = zero;
  for (int kt = 0; kt < 4; ++kt) {
    const float* ar = Ab + (r0 + lr) * Nv + kt * 32 + lg * 8;
    const float4 a0 = *(const float4*)(ar);
    const float4 a1 = *(const float4*)(ar + 4);
    const float as_[8] = {a0.x, a0.y, a0.z, a0.w, a1.x, a1.y, a1.z, a1.w};
    B8U af;
#pragma unroll
    for (int j = 0; j < 8; ++j) af.s[j] = (short)f2bf(as_[j]);
#pragma unroll
    for (int n = 0; n < 16; ++n) {
      const int voff = vswz(n * 16 + lr, kt * 32 + lg * 8);
      const bf8 vf = *(const bf8*)(vt + voff);
      aO[n] = MFMA16(af.v, vf, aO[n]);
    }
  }
#pragma unroll
  for (int n = 0; n < 16; ++n) {
#pragma unroll
    for (int r = 0; r < 4; ++r) {
      ob[(r0 + 4 * lg + r) * P2v + n * 16 + lr] = aO[n][r];
    }
  }
}

extern "C" void kernel_launch(void* const* d_in, const int* in_sizes, int n_in,
                              void* d_out, int out_size, void* d_ws,
                              size_t ws_size, hipStream_t stream) {
  const float* x = (const float*)d_in[0];
  const float* Wq = (const float*)d_in[1];
  const float* Wk = (const float*)d_in[2];
  const float* Wv = (const float*)d_in[3];
  float* out = (float*)d_out;

  // ws layout: W fragments (256 KB) then S (33.55 MB)
  unsigned short* wqh = (unsigned short*)d_ws;
  unsigned short* wql = wqh + 16384;
  unsigned short* wkh = wql + 16384;
  unsigned short* wkl = wkh + 16384;
  unsigned short* wvf = wkl + 16384;  // 65536 elems
  float* S = (float*)((char*)d_ws + 262144);

  hipLaunchKernelGGL(prep_w_kernel, dim3(384), dim3(256), 0, stream, Wq, Wk,
                     Wv, wqh, wql, wkh, wkl, wvf);
  hipLaunchKernelGGL(qk_kernel, dim3(Bv * Tv), dim3(512), 0, stream, x, wqh,
                     wql, wkh, wkl, S);
  hipLaunchKernelGGL(softmax_t_kernel, dim3(Bv * Nv * Nv / 256), dim3(256), 0,
                     stream, S);
  hipLaunchKernelGGL(av_kernel, dim3(Bv * Tv), dim3(512), 0, stream, x, wvf, S,
                     out);
}